// Round 1
// 137.140 us; speedup vs baseline: 1.0091x; 1.0091x over previous
//
#include <hip/hip_runtime.h>
#include <hip/hip_bf16.h>
#include <math.h>

#define B_   8
#define C_   192
#define N_   3136
#define K_   9
#define OUT_ 384
#define G_   4
#define CG_  96   // in-channels per group (2C/G)
#define OG_  96   // out-channels per group
#define NTILES 49 // N_/64

typedef __attribute__((ext_vector_type(8))) short short8;
typedef __attribute__((ext_vector_type(4))) float floatx4;

// ---------------- ws layout (bytes) ----------------
// xT : B*N*C   bf16 =  9,633,792
// y  : B*OUT*N bf16 = 19,267,584
// sp : B*G*49*192 f32 = 1,204,224   (per-block BN partials)
// wb : OUT*CG  bf16 =     73,728
// st : OUT*2   f32
static const size_t OFF_XT = 0;
static const size_t OFF_Y  = 9633792;
static const size_t OFF_SP = OFF_Y  + 19267584;
static const size_t OFF_WB = OFF_SP + 1204224;
static const size_t OFF_ST = OFF_WB + 73728;

__device__ inline short f2bs(float f) {
    __hip_bfloat16 h = __float2bfloat16(f);
    union { __hip_bfloat16 h; short s; } u; u.h = h; return u.s;
}
__device__ inline float blo(unsigned int u) {
    unsigned int v = u << 16; return __builtin_bit_cast(float, v);
}
__device__ inline float bhi(unsigned int u) {
    unsigned int v = u & 0xffff0000u; return __builtin_bit_cast(float, v);
}
__device__ inline unsigned int packbf(float lo, float hi) {
    unsigned int l = (unsigned int)(unsigned short)f2bs(lo);
    unsigned int h = (unsigned int)(unsigned short)f2bs(hi);
    return (h << 16) | l;
}

// ---- Kernel A: transpose x [B,C,N] f32 -> xT [B,N,C] bf16; fold W->bf16 ----
__global__ __launch_bounds__(256) void k_transpose(const float* __restrict__ x,
                                                   __hip_bfloat16* __restrict__ xT,
                                                   const float* __restrict__ w,
                                                   __hip_bfloat16* __restrict__ wb) {
    // weight conversion folded into 144 of the 392 y==0 blocks (36864 = 144*256)
    if (blockIdx.y == 0) {
        int j = blockIdx.x * NTILES + blockIdx.z;
        if (j < 144) {
            int i = j * 256 + threadIdx.x;
            wb[i] = __float2bfloat16(w[i]);
        }
    }
    __shared__ float tile[64][65];
    int b  = blockIdx.x;
    int cb = blockIdx.y * 64;
    int nb = blockIdx.z * 64;
    int tid = threadIdx.x;
    int tn  = tid & 63;
    int tc4 = tid >> 6;
    const float* xp = x + ((size_t)b * C_ + cb) * N_ + nb;
    #pragma unroll
    for (int i = 0; i < 16; ++i) {
        int c = tc4 + i * 4;
        tile[c][tn] = xp[(size_t)c * N_ + tn];
    }
    __syncthreads();
    __hip_bfloat16* xo = xT + ((size_t)b * N_ + nb) * C_ + cb;
    int tcl = tid & 63;
    int tn4 = tid >> 6;
    #pragma unroll
    for (int i = 0; i < 16; ++i) {
        int n = tn4 + i * 4;
        xo[(size_t)n * C_ + tcl] = __float2bfloat16(tile[tcl][n]);
    }
}

// ---- Kernel C: FUSED gather + max-relative + grouped 1x1 conv (bf16 MFMA) ----
// Per block (b,g,nt): gather the 48-channel slice for 64 nodes into LDS
// (interleaved [x, rel] pairs, exactly the xc layout), then MFMA from LDS.
// Gather L2 traffic is invariant vs the old standalone kernel: each group
// reads only its 24-dword slice, 4 groups x 24 = 96 dwords = full row.
__global__ __launch_bounds__(256) void k_conv(const __hip_bfloat16* __restrict__ xT,
                                              const int* __restrict__ eidx,
                                              const __hip_bfloat16* __restrict__ Wb,
                                              const float* __restrict__ bias,
                                              __hip_bfloat16* __restrict__ y,
                                              float* __restrict__ sp) {
    int b  = blockIdx.x;
    int g  = blockIdx.y;
    int nt = blockIdx.z;
    int tid  = threadIdx.x;
    int lane = tid & 63;
    int wid  = tid >> 6;
    int n0   = nt * 64 + wid * 16;
    int col  = lane & 15;
    int quad = lane >> 4;

    __shared__ short wl[OG_ * CG_];        // 18,432 B, fragment-order swizzled
    __shared__ unsigned int xcl[64][50];   // 12,800 B, +2 dword pad: stride 50
                                           // -> 18*col mod 32 covers all 16 even
                                           //    residues => conflict-free b128 reads
    __shared__ float red[4][192];

    // ---- stage group-g weights: coalesced global uint2 -> swizzled LDS ----
    const uint2* src = reinterpret_cast<const uint2*>(Wb + (size_t)g * OG_ * CG_);
    #pragma unroll
    for (int it = 0; it < 9; ++it) {
        int i  = it * 256 + tid;      // uint2 index, 2304 total
        uint2 v = src[i];
        int gs = i * 4;               // short index within group block
        int oc = gs / CG_;
        int cg = gs - oc * CG_;
        int mt = oc >> 4, cl = oc & 15;
        int kc = cg >> 5, rem = cg & 31;
        int qd = rem >> 3, j = rem & 7;   // j in {0,4}
        int pos = (((mt * 3 + kc) * 4 + qd) * 16 + cl) * 8 + j;
        *reinterpret_cast<uint2*>(&wl[pos]) = v;
    }

    // ---- fused gather + max-relative into LDS xc tile ----
    // 8 lanes per node, 32 nodes per pass, 2 passes.
    int lane8 = tid & 7;
    int slot  = tid >> 3;              // 0..31
    const unsigned int* xb =
        reinterpret_cast<const unsigned int*>(xT + (size_t)b * N_ * C_);
    #pragma unroll
    for (int p = 0; p < 2; ++p) {
        int nloc = p * 32 + slot;      // node within tile, 0..63
        int n    = nt * 64 + nloc;
        const int* e0 = eidx + ((size_t)b * N_ + n) * K_;                        // x_j
        const int* e1 = eidx + (size_t)B_ * N_ * K_ + ((size_t)b * N_ + n) * K_; // x_i
        int o0[K_], o1[K_];
        #pragma unroll
        for (int k = 0; k < K_; ++k) {
            o0[k] = e0[k] * (C_ / 2) + 24 * g;
            o1[k] = e1[k] * (C_ / 2) + 24 * g;
        }
        const unsigned int* xn = xb + (size_t)n * (C_ / 2) + 24 * g;
        #pragma unroll
        for (int it = 0; it < 3; ++it) {
            int c2 = lane8 + it * 8;   // slice dword 0..23 (channels 48g+2c2,+1)
            unsigned int ctr = xn[c2];
            float r0 = -INFINITY, r1 = -INFINITY;
            #pragma unroll
            for (int k = 0; k < K_; ++k) {
                unsigned int uj = xb[(size_t)o0[k] + c2];
                unsigned int ui = xb[(size_t)o1[k] + c2];
                r0 = fmaxf(r0, blo(uj) - blo(ui));
                r1 = fmaxf(r1, bhi(uj) - bhi(ui));
            }
            uint2 o;
            o.x = packbf(blo(ctr), r0);
            o.y = packbf(bhi(ctr), r1);
            *reinterpret_cast<uint2*>(&xcl[nloc][2 * c2]) = o;
        }
    }
    __syncthreads();

    // ---- MFMA loop, B-fragments straight from the LDS xc tile ----
    floatx4 acc[6];
    #pragma unroll
    for (int mt = 0; mt < 6; ++mt) acc[mt] = (floatx4){0.f, 0.f, 0.f, 0.f};
    #pragma unroll
    for (int kc = 0; kc < 3; ++kc) {
        short8 xf = *reinterpret_cast<const short8*>(
            &xcl[wid * 16 + col][kc * 16 + quad * 4]);
        #pragma unroll
        for (int mt = 0; mt < 6; ++mt) {
            short8 wf = *reinterpret_cast<const short8*>(
                &wl[(((mt * 3 + kc) * 4 + quad) * 16 + col) * 8]);
            acc[mt] = __builtin_amdgcn_mfma_f32_16x16x32_bf16(wf, xf, acc[mt], 0, 0, 0);
        }
    }

    // D layout: col(n) = lane&15, row(oc) = quad*4 + reg
    #pragma unroll
    for (int mt = 0; mt < 6; ++mt) {
        #pragma unroll
        for (int r = 0; r < 4; ++r) {
            int ol = mt * 16 + quad * 4 + r;     // oc within group, 0..95
            int oc = g * OG_ + ol;
            float v = acc[mt][r] + bias[oc];
            y[((size_t)b * OUT_ + oc) * N_ + n0 + col] = __float2bfloat16(v);
            float s = v, ss = v * v;
            #pragma unroll
            for (int m = 1; m <= 8; m <<= 1) {
                s  += __shfl_xor(s, m);
                ss += __shfl_xor(ss, m);
            }
            if (col == 0) {
                red[wid][ol]      = s;
                red[wid][96 + ol] = ss;
            }
        }
    }
    __syncthreads();
    if (tid < 192) {
        float t = red[0][tid] + red[1][tid] + red[2][tid] + red[3][tid];
        sp[(((size_t)b * G_ + g) * NTILES + nt) * 192 + tid] = t;
    }
}

// ---- Kernel D: fold per-block partials into st[OUT*2] ----
__global__ __launch_bounds__(256) void k_redstats(const float* __restrict__ sp,
                                                  float* __restrict__ st) {
    int oc = blockIdx.x;
    int g  = oc / OG_;
    int o  = oc % OG_;
    float s = 0.f, ss = 0.f;
    for (int e = threadIdx.x; e < B_ * NTILES; e += 256) {
        int b  = e / NTILES;
        int nt = e % NTILES;
        const float* p = sp + (((size_t)b * G_ + g) * NTILES + nt) * 192;
        s  += p[o];
        ss += p[96 + o];
    }
    #pragma unroll
    for (int m = 32; m; m >>= 1) {
        s  += __shfl_xor(s, m);
        ss += __shfl_xor(ss, m);
    }
    __shared__ float ls[4], lss[4];
    int wid = threadIdx.x >> 6, lane = threadIdx.x & 63;
    if (lane == 0) { ls[wid] = s; lss[wid] = ss; }
    __syncthreads();
    if (threadIdx.x == 0) {
        st[oc]        = ls[0] + ls[1] + ls[2] + ls[3];
        st[OUT_ + oc] = lss[0] + lss[1] + lss[2] + lss[3];
    }
}

// ---- Kernel E: BN (batch stats) + exact GELU, write fp32 out [B,OUT,N] ----
__global__ __launch_bounds__(256) void k_bn_gelu(const __hip_bfloat16* __restrict__ y,
                                                 const float* __restrict__ st,
                                                 const float* __restrict__ gamma,
                                                 const float* __restrict__ beta,
                                                 float* __restrict__ out) {
    size_t base = ((size_t)blockIdx.x * 256 + threadIdx.x) * 4;
    int oc = (int)((base / N_) % OUT_);
    const float invM = 1.0f / (float)(B_ * N_);
    float s = st[oc], ss = st[OUT_ + oc];
    float mean = s * invM;
    float var  = ss * invM - mean * mean;
    float inv  = 1.0f / sqrtf(var + 1e-5f);
    float sc = gamma[oc] * inv;
    float sh = beta[oc] - mean * sc;

    const __hip_bfloat162* yp = reinterpret_cast<const __hip_bfloat162*>(y + base);
    __hip_bfloat162 p0 = yp[0], p1 = yp[1];
    float v[4] = { __bfloat162float(p0.x), __bfloat162float(p0.y),
                   __bfloat162float(p1.x), __bfloat162float(p1.y) };
    float4 o;
    float* op = &o.x;
    #pragma unroll
    for (int j = 0; j < 4; ++j) {
        float t = v[j] * sc + sh;
        op[j] = 0.5f * t * (1.0f + erff(t * 0.70710678118654752f));
    }
    *reinterpret_cast<float4*>(out + base) = o;
}

extern "C" void kernel_launch(void* const* d_in, const int* in_sizes, int n_in,
                              void* d_out, int out_size, void* d_ws, size_t ws_size,
                              hipStream_t stream) {
    const float* x      = (const float*)d_in[0];
    const int*   eidx   = (const int*)d_in[1];
    const float* conv_w = (const float*)d_in[2];
    const float* conv_b = (const float*)d_in[3];
    const float* gamma  = (const float*)d_in[4];
    const float* beta   = (const float*)d_in[5];
    float* out = (float*)d_out;

    char* ws = (char*)d_ws;
    __hip_bfloat16* xT = (__hip_bfloat16*)(ws + OFF_XT);
    __hip_bfloat16* y  = (__hip_bfloat16*)(ws + OFF_Y);
    float*          sp = (float*)(ws + OFF_SP);
    __hip_bfloat16* wb = (__hip_bfloat16*)(ws + OFF_WB);
    float*          st = (float*)(ws + OFF_ST);

    k_transpose<<<dim3(B_, C_ / 64, N_ / 64), 256, 0, stream>>>(x, xT, conv_w, wb);
    k_conv<<<dim3(B_, G_, NTILES), 256, 0, stream>>>(xT, eidx, wb, conv_b, y, sp);
    k_redstats<<<OUT_, 256, 0, stream>>>(sp, st);
    k_bn_gelu<<<dim3((B_ * OUT_ * N_) / (256 * 4)), 256, 0, stream>>>(y, st, gamma, beta, out);
}

// Round 3
// 124.030 us; speedup vs baseline: 1.1157x; 1.1057x over previous
//
#include <hip/hip_runtime.h>
#include <hip/hip_bf16.h>
#include <math.h>

#define B_   8
#define C_   192
#define N_   3136
#define K_   9
#define OUT_ 384
#define G_   4
#define CG_  96   // in-channels per group (2C/G)
#define OG_  96   // out-channels per group
#define NTILES 49 // N_/64

typedef __attribute__((ext_vector_type(8))) short short8;
typedef __attribute__((ext_vector_type(4))) float floatx4;
typedef __attribute__((ext_vector_type(3))) unsigned int uintx3;

// ---------------- ws layout (bytes) ----------------
// xT : B*N*C   bf16 =  9,633,792
// wb : OUT*CG  bf16 =     73,728
// st : OUT*2   f32  =      3,072   (atomic-accumulated BN stats)
static const size_t OFF_XT = 0;
static const size_t OFF_WB = 9633792;
static const size_t OFF_ST = OFF_WB + 73728;

__device__ inline short f2bs(float f) {
    __hip_bfloat16 h = __float2bfloat16(f);
    union { __hip_bfloat16 h; short s; } u; u.h = h; return u.s;
}
__device__ inline float blo(unsigned int u) {
    unsigned int v = u << 16; return __builtin_bit_cast(float, v);
}
__device__ inline float bhi(unsigned int u) {
    unsigned int v = u & 0xffff0000u; return __builtin_bit_cast(float, v);
}
__device__ inline unsigned int packbf(float lo, float hi) {
    unsigned int l = (unsigned int)(unsigned short)f2bs(lo);
    unsigned int h = (unsigned int)(unsigned short)f2bs(hi);
    return (h << 16) | l;
}

// ---- Kernel A: transpose x [B,C,N] f32 -> xT [B,N,C] bf16; W->bf16; st=0 ----
__global__ __launch_bounds__(256) void k_transpose(const float* __restrict__ x,
                                                   __hip_bfloat16* __restrict__ xT,
                                                   const float* __restrict__ w,
                                                   __hip_bfloat16* __restrict__ wb,
                                                   float* __restrict__ st) {
    // weight conversion folded into 144 of the 392 y==0 blocks
    if (blockIdx.y == 0) {
        int j = blockIdx.x * NTILES + blockIdx.z;
        if (j < 144) {
            int i = j * 256 + threadIdx.x;
            wb[i] = __float2bfloat16(w[i]);
        }
    }
    // zero the atomic stats buffer (ws is re-poisoned every iteration)
    if (blockIdx.y == 1 && blockIdx.z == 0 && blockIdx.x == 0) {
        #pragma unroll
        for (int i = 0; i < 3; ++i) st[i * 256 + threadIdx.x] = 0.f;
    }
    __shared__ float tile[64][65];
    int b  = blockIdx.x;
    int cb = blockIdx.y * 64;
    int nb = blockIdx.z * 64;
    int tid = threadIdx.x;
    int tn  = tid & 63;
    int tc4 = tid >> 6;
    const float* xp = x + ((size_t)b * C_ + cb) * N_ + nb;
    #pragma unroll
    for (int i = 0; i < 16; ++i) {
        int c = tc4 + i * 4;
        tile[c][tn] = xp[(size_t)c * N_ + tn];
    }
    __syncthreads();
    __hip_bfloat16* xo = xT + ((size_t)b * N_ + nb) * C_ + cb;
    #pragma unroll
    for (int i = 0; i < 16; ++i) {
        int n = tc4 + i * 4;
        xo[(size_t)n * C_ + tn] = __float2bfloat16(tile[tn][n]);
    }
}

// ---- Kernel C: fused gather + max-rel + grouped conv + atomic BN partials ----
// VMEM-lean gather: eidx staged in LDS (coalesced), neighbor rows read as
// dwordx3 (one instr per 12B slice chunk): 38 gather VMEM/thread vs 150.
__global__ __launch_bounds__(256) void k_conv(const __hip_bfloat16* __restrict__ xT,
                                              const int* __restrict__ eidx,
                                              const __hip_bfloat16* __restrict__ Wb,
                                              __hip_bfloat16* __restrict__ y,
                                              float* __restrict__ st) {
    int b  = blockIdx.x;
    int g  = blockIdx.y;
    int nt = blockIdx.z;
    int tid  = threadIdx.x;
    int lane = tid & 63;
    int wid  = tid >> 6;
    int n0   = nt * 64 + wid * 16;
    int col  = lane & 15;
    int quad = lane >> 4;

    __shared__ short wl[OG_ * CG_];        // 18,432 B, fragment-order swizzled
    __shared__ unsigned int xcl[64][50];   // 12,800 B, stride-50 pad (conflict-lean)
    __shared__ int eL[2][576];             //  4,608 B staged indices
    __shared__ float red[4][192];

    // ---- stage group-g weights: coalesced uint2 -> fragment-swizzled LDS ----
    const uint2* src = reinterpret_cast<const uint2*>(Wb + (size_t)g * OG_ * CG_);
    #pragma unroll
    for (int it = 0; it < 9; ++it) {
        int i  = it * 256 + tid;      // uint2 index, 2304 total
        uint2 v = src[i];
        int gs = i * 4;
        int oc = gs / CG_;
        int cg = gs - oc * CG_;
        int mt = oc >> 4, cl = oc & 15;
        int kc = cg >> 5, rem = cg & 31;
        int qd = rem >> 3, j = rem & 7;   // j in {0,4}
        int pos = (((mt * 3 + kc) * 4 + qd) * 16 + cl) * 8 + j;
        *reinterpret_cast<uint2*>(&wl[pos]) = v;
    }

    // ---- stage edge indices for this tile (coalesced) ----
    {
        const int* e0b = eidx + ((size_t)b * N_ + nt * 64) * K_;
        const int* e1b = eidx + (size_t)B_ * N_ * K_ + ((size_t)b * N_ + nt * 64) * K_;
        for (int e = tid; e < 576; e += 256) {
            eL[0][e] = e0b[e];
            eL[1][e] = e1b[e];
        }
    }
    __syncthreads();

    // ---- fused gather + max-relative into LDS xc tile ----
    // 8 lanes/node, each lane owns 3 consecutive dwords of the 24-dword slice.
    int lane8 = tid & 7;
    int slot  = tid >> 3;              // 0..31
    const unsigned int* xb =
        reinterpret_cast<const unsigned int*>(xT + (size_t)b * N_ * C_);
    int cbase = 24 * g + 3 * lane8;
    #pragma unroll
    for (int p = 0; p < 2; ++p) {
        int nloc = p * 32 + slot;      // node within tile, 0..63
        int n    = nt * 64 + nloc;
        uintx3 ctr = *reinterpret_cast<const uintx3*>(xb + (size_t)n * 96 + cbase);
        float m0 = -INFINITY, m1 = -INFINITY, m2 = -INFINITY;
        float m3 = -INFINITY, m4 = -INFINITY, m5 = -INFINITY;
        #pragma unroll
        for (int k = 0; k < K_; ++k) {
            int oj = eL[0][nloc * 9 + k] * 96 + cbase;
            int oi = eL[1][nloc * 9 + k] * 96 + cbase;
            uintx3 vj = *reinterpret_cast<const uintx3*>(xb + oj);
            uintx3 vi = *reinterpret_cast<const uintx3*>(xb + oi);
            m0 = fmaxf(m0, blo(vj.x) - blo(vi.x));
            m1 = fmaxf(m1, bhi(vj.x) - bhi(vi.x));
            m2 = fmaxf(m2, blo(vj.y) - blo(vi.y));
            m3 = fmaxf(m3, bhi(vj.y) - bhi(vi.y));
            m4 = fmaxf(m4, blo(vj.z) - blo(vi.z));
            m5 = fmaxf(m5, bhi(vj.z) - bhi(vi.z));
        }
        unsigned int* orow = &xcl[nloc][6 * lane8];
        uint2 w0, w1, w2;
        w0.x = packbf(blo(ctr.x), m0); w0.y = packbf(bhi(ctr.x), m1);
        w1.x = packbf(blo(ctr.y), m2); w1.y = packbf(bhi(ctr.y), m3);
        w2.x = packbf(blo(ctr.z), m4); w2.y = packbf(bhi(ctr.z), m5);
        reinterpret_cast<uint2*>(orow)[0] = w0;
        reinterpret_cast<uint2*>(orow)[1] = w1;
        reinterpret_cast<uint2*>(orow)[2] = w2;
    }
    __syncthreads();

    // ---- MFMA from LDS (no bias: it cancels exactly under batch-stat BN) ----
    floatx4 acc[6];
    #pragma unroll
    for (int mt = 0; mt < 6; ++mt) acc[mt] = (floatx4){0.f, 0.f, 0.f, 0.f};
    #pragma unroll
    for (int kc = 0; kc < 3; ++kc) {
        short8 xf = *reinterpret_cast<const short8*>(
            &xcl[wid * 16 + col][kc * 16 + quad * 4]);
        #pragma unroll
        for (int mt = 0; mt < 6; ++mt) {
            short8 wf = *reinterpret_cast<const short8*>(
                &wl[(((mt * 3 + kc) * 4 + quad) * 16 + col) * 8]);
            acc[mt] = __builtin_amdgcn_mfma_f32_16x16x32_bf16(wf, xf, acc[mt], 0, 0, 0);
        }
    }

    // D layout: col(n) = lane&15, row(oc) = quad*4 + reg
    #pragma unroll
    for (int mt = 0; mt < 6; ++mt) {
        #pragma unroll
        for (int r = 0; r < 4; ++r) {
            int ol = mt * 16 + quad * 4 + r;     // oc within group, 0..95
            int oc = g * OG_ + ol;
            float v = acc[mt][r];
            y[((size_t)b * OUT_ + oc) * N_ + n0 + col] = __float2bfloat16(v);
            float s = v, ss = v * v;
            #pragma unroll
            for (int m = 1; m <= 8; m <<= 1) {
                s  += __shfl_xor(s, m);
                ss += __shfl_xor(ss, m);
            }
            if (col == 0) {
                red[wid][ol]      = s;
                red[wid][96 + ol] = ss;
            }
        }
    }
    __syncthreads();
    if (tid < 192) {
        float t = red[0][tid] + red[1][tid] + red[2][tid] + red[3][tid];
        if (tid < 96) atomicAdd(&st[g * OG_ + tid], t);
        else          atomicAdd(&st[OUT_ + g * OG_ + (tid - 96)], t);
    }
}

// ---- Kernel E: BN (batch stats) + exact GELU, 8 elems/thread ----
__global__ __launch_bounds__(256) void k_bn_gelu(const __hip_bfloat16* __restrict__ y,
                                                 const float* __restrict__ st,
                                                 const float* __restrict__ gamma,
                                                 const float* __restrict__ beta,
                                                 float* __restrict__ out) {
    size_t base = ((size_t)blockIdx.x * 256 + threadIdx.x) * 8;
    int oc = (int)((base / N_) % OUT_);       // N_ % 8 == 0 -> uniform oc per 8
    const float invM = 1.0f / (float)(B_ * N_);
    float s = st[oc], ss = st[OUT_ + oc];
    float mean = s * invM;
    float var  = ss * invM - mean * mean;
    float inv  = 1.0f / sqrtf(var + 1e-5f);
    float sc = gamma[oc] * inv;
    float sh = beta[oc] - mean * sc;

    short8 v8 = *reinterpret_cast<const short8*>(y + base);
    float4 o0, o1;
    float* op0 = &o0.x;
    float* op1 = &o1.x;
    #pragma unroll
    for (int j = 0; j < 8; ++j) {
        unsigned int u = ((unsigned int)(unsigned short)v8[j]) << 16;
        float t = __builtin_bit_cast(float, u) * sc + sh;
        float r = 0.5f * t * (1.0f + erff(t * 0.70710678118654752f));
        if (j < 4) op0[j] = r; else op1[j - 4] = r;
    }
    *reinterpret_cast<float4*>(out + base)     = o0;
    *reinterpret_cast<float4*>(out + base + 4) = o1;
}

extern "C" void kernel_launch(void* const* d_in, const int* in_sizes, int n_in,
                              void* d_out, int out_size, void* d_ws, size_t ws_size,
                              hipStream_t stream) {
    const float* x      = (const float*)d_in[0];
    const int*   eidx   = (const int*)d_in[1];
    const float* conv_w = (const float*)d_in[2];
    // d_in[3] = conv_b: unused (bias cancels exactly under batch-stat BN)
    const float* gamma  = (const float*)d_in[4];
    const float* beta   = (const float*)d_in[5];
    float* out = (float*)d_out;

    char* ws = (char*)d_ws;
    __hip_bfloat16* xT = (__hip_bfloat16*)(ws + OFF_XT);
    __hip_bfloat16* wb = (__hip_bfloat16*)(ws + OFF_WB);
    float*          st = (float*)(ws + OFF_ST);
    __hip_bfloat16* y  = (__hip_bfloat16*)(ws + OFF_ST + 3072);

    k_transpose<<<dim3(B_, C_ / 64, N_ / 64), 256, 0, stream>>>(x, xT, conv_w, wb, st);
    k_conv<<<dim3(B_, G_, NTILES), 256, 0, stream>>>(xT, eidx, wb, y, st);
    k_bn_gelu<<<dim3((B_ * OUT_ * N_) / (256 * 8)), 256, 0, stream>>>(y, st, gamma, beta, out);
}

// Round 4
// 123.912 us; speedup vs baseline: 1.1168x; 1.0010x over previous
//
#include <hip/hip_runtime.h>
#include <hip/hip_bf16.h>
#include <math.h>

#define B_   8
#define C_   192
#define N_   3136
#define K_   9
#define OUT_ 384
#define G_   4
#define CG_  96   // in-channels per group (2C/G)
#define OG_  96   // out-channels per group
#define NTILES 49 // N_/64

typedef __attribute__((ext_vector_type(8))) short short8;
typedef __attribute__((ext_vector_type(4))) float floatx4;
typedef __attribute__((ext_vector_type(3))) unsigned int uintx3;

// ---------------- ws layout (bytes) ----------------
// xT : B*N*C   bf16 =  9,633,792
// wb : OUT*CG  bf16 =     73,728
// st : OUT*2   f32  =      3,072   (atomic-accumulated BN stats)
// y  : B*OUT*N bf16 (after st)
static const size_t OFF_XT = 0;
static const size_t OFF_WB = 9633792;
static const size_t OFF_ST = OFF_WB + 73728;

__device__ inline short f2bs(float f) {
    __hip_bfloat16 h = __float2bfloat16(f);
    union { __hip_bfloat16 h; short s; } u; u.h = h; return u.s;
}
__device__ inline float blo(unsigned int u) {
    unsigned int v = u << 16; return __builtin_bit_cast(float, v);
}
__device__ inline float bhi(unsigned int u) {
    unsigned int v = u & 0xffff0000u; return __builtin_bit_cast(float, v);
}
__device__ inline unsigned int packbf(float lo, float hi) {
    unsigned int l = (unsigned int)(unsigned short)f2bs(lo);
    unsigned int h = (unsigned int)(unsigned short)f2bs(hi);
    return (h << 16) | l;
}

// ---- Kernel A: transpose x [B,C,N] f32 -> xT [B,N,C] bf16; W->bf16; st=0 ----
__global__ __launch_bounds__(256) void k_transpose(const float* __restrict__ x,
                                                   __hip_bfloat16* __restrict__ xT,
                                                   const float* __restrict__ w,
                                                   __hip_bfloat16* __restrict__ wb,
                                                   float* __restrict__ st) {
    // weight conversion folded into 144 of the 392 y==0 blocks
    if (blockIdx.y == 0) {
        int j = blockIdx.x * NTILES + blockIdx.z;
        if (j < 144) {
            int i = j * 256 + threadIdx.x;
            wb[i] = __float2bfloat16(w[i]);
        }
    }
    // zero the atomic stats buffer (ws is re-poisoned every iteration)
    if (blockIdx.y == 1 && blockIdx.z == 0 && blockIdx.x == 0) {
        #pragma unroll
        for (int i = 0; i < 3; ++i) st[i * 256 + threadIdx.x] = 0.f;
    }
    __shared__ float tile[64][65];
    int b  = blockIdx.x;
    int cb = blockIdx.y * 64;
    int nb = blockIdx.z * 64;
    int tid = threadIdx.x;
    int tn  = tid & 63;
    int tc4 = tid >> 6;
    const float* xp = x + ((size_t)b * C_ + cb) * N_ + nb;
    #pragma unroll
    for (int i = 0; i < 16; ++i) {
        int c = tc4 + i * 4;
        tile[c][tn] = xp[(size_t)c * N_ + tn];
    }
    __syncthreads();
    __hip_bfloat16* xo = xT + ((size_t)b * N_ + nb) * C_ + cb;
    #pragma unroll
    for (int i = 0; i < 16; ++i) {
        int n = tc4 + i * 4;
        xo[(size_t)n * C_ + tn] = __float2bfloat16(tile[tn][n]);
    }
}

// ---- Kernel C: fused gather + max-rel + grouped conv + atomic BN partials ----
// launch_bounds(256,4): 128-VGPR cap == LDS-imposed occupancy (4 blk/CU,
// 16 waves) -> allocator has room to keep all 18 scattered gather loads of a
// pass in flight (vj[9]/vi[9] register arrays) instead of serializing the
// LDS-idx -> addr -> L2-load -> fmax chain per k (R3: VGPR=52, 53 us).
__global__ __launch_bounds__(256, 4) void k_conv(const __hip_bfloat16* __restrict__ xT,
                                                 const int* __restrict__ eidx,
                                                 const __hip_bfloat16* __restrict__ Wb,
                                                 __hip_bfloat16* __restrict__ y,
                                                 float* __restrict__ st) {
    int b  = blockIdx.x;
    int g  = blockIdx.y;
    int nt = blockIdx.z;
    int tid  = threadIdx.x;
    int lane = tid & 63;
    int wid  = tid >> 6;
    int n0   = nt * 64 + wid * 16;
    int col  = lane & 15;
    int quad = lane >> 4;

    __shared__ short wl[OG_ * CG_];        // 18,432 B, fragment-order swizzled
    __shared__ unsigned int xcl[64][50];   // 12,800 B, stride-50 pad
    __shared__ int eL[2][576];             //  4,608 B staged indices
    __shared__ float red[4][192];

    // ---- stage group-g weights: coalesced uint2 -> fragment-swizzled LDS ----
    const uint2* src = reinterpret_cast<const uint2*>(Wb + (size_t)g * OG_ * CG_);
    #pragma unroll
    for (int it = 0; it < 9; ++it) {
        int i  = it * 256 + tid;      // uint2 index, 2304 total
        uint2 v = src[i];
        int gs = i * 4;
        int oc = gs / CG_;
        int cg = gs - oc * CG_;
        int mt = oc >> 4, cl = oc & 15;
        int kc = cg >> 5, rem = cg & 31;
        int qd = rem >> 3, j = rem & 7;   // j in {0,4}
        int pos = (((mt * 3 + kc) * 4 + qd) * 16 + cl) * 8 + j;
        *reinterpret_cast<uint2*>(&wl[pos]) = v;
    }

    // ---- stage edge indices for this tile (coalesced) ----
    {
        const int* e0b = eidx + ((size_t)b * N_ + nt * 64) * K_;
        const int* e1b = eidx + (size_t)B_ * N_ * K_ + ((size_t)b * N_ + nt * 64) * K_;
        for (int e = tid; e < 576; e += 256) {
            eL[0][e] = e0b[e];
            eL[1][e] = e1b[e];
        }
    }
    __syncthreads();

    // ---- fused gather + max-relative into LDS xc tile ----
    // 8 lanes/node, each lane owns 3 consecutive dwords of the 24-dword slice.
    int lane8 = tid & 7;
    int slot  = tid >> 3;              // 0..31
    const unsigned int* xb =
        reinterpret_cast<const unsigned int*>(xT + (size_t)b * N_ * C_);
    int cbase = 24 * g + 3 * lane8;
    #pragma unroll
    for (int p = 0; p < 2; ++p) {
        int nloc = p * 32 + slot;      // node within tile, 0..63
        int n    = nt * 64 + nloc;
        // hoist all index reads, then batch-issue all scattered loads
        int a0[K_], a1[K_];
        #pragma unroll
        for (int k = 0; k < K_; ++k) {
            a0[k] = eL[0][nloc * 9 + k] * 96 + cbase;
            a1[k] = eL[1][nloc * 9 + k] * 96 + cbase;
        }
        uintx3 ctr = *reinterpret_cast<const uintx3*>(xb + (size_t)n * 96 + cbase);
        uintx3 vj[K_], vi[K_];
        #pragma unroll
        for (int k = 0; k < K_; ++k)
            vj[k] = *reinterpret_cast<const uintx3*>(xb + (size_t)a0[k]);
        #pragma unroll
        for (int k = 0; k < K_; ++k)
            vi[k] = *reinterpret_cast<const uintx3*>(xb + (size_t)a1[k]);
        float m0 = -INFINITY, m1 = -INFINITY, m2 = -INFINITY;
        float m3 = -INFINITY, m4 = -INFINITY, m5 = -INFINITY;
        #pragma unroll
        for (int k = 0; k < K_; ++k) {
            m0 = fmaxf(m0, blo(vj[k].x) - blo(vi[k].x));
            m1 = fmaxf(m1, bhi(vj[k].x) - bhi(vi[k].x));
            m2 = fmaxf(m2, blo(vj[k].y) - blo(vi[k].y));
            m3 = fmaxf(m3, bhi(vj[k].y) - bhi(vi[k].y));
            m4 = fmaxf(m4, blo(vj[k].z) - blo(vi[k].z));
            m5 = fmaxf(m5, bhi(vj[k].z) - bhi(vi[k].z));
        }
        unsigned int* orow = &xcl[nloc][6 * lane8];
        uint2 w0, w1, w2;
        w0.x = packbf(blo(ctr.x), m0); w0.y = packbf(bhi(ctr.x), m1);
        w1.x = packbf(blo(ctr.y), m2); w1.y = packbf(bhi(ctr.y), m3);
        w2.x = packbf(blo(ctr.z), m4); w2.y = packbf(bhi(ctr.z), m5);
        reinterpret_cast<uint2*>(orow)[0] = w0;
        reinterpret_cast<uint2*>(orow)[1] = w1;
        reinterpret_cast<uint2*>(orow)[2] = w2;
    }
    __syncthreads();

    // ---- MFMA from LDS (no bias: it cancels exactly under batch-stat BN) ----
    floatx4 acc[6];
    #pragma unroll
    for (int mt = 0; mt < 6; ++mt) acc[mt] = (floatx4){0.f, 0.f, 0.f, 0.f};
    #pragma unroll
    for (int kc = 0; kc < 3; ++kc) {
        short8 xf = *reinterpret_cast<const short8*>(
            &xcl[wid * 16 + col][kc * 16 + quad * 4]);
        #pragma unroll
        for (int mt = 0; mt < 6; ++mt) {
            short8 wf = *reinterpret_cast<const short8*>(
                &wl[(((mt * 3 + kc) * 4 + quad) * 16 + col) * 8]);
            acc[mt] = __builtin_amdgcn_mfma_f32_16x16x32_bf16(wf, xf, acc[mt], 0, 0, 0);
        }
    }

    // D layout: col(n) = lane&15, row(oc) = quad*4 + reg
    #pragma unroll
    for (int mt = 0; mt < 6; ++mt) {
        #pragma unroll
        for (int r = 0; r < 4; ++r) {
            int ol = mt * 16 + quad * 4 + r;     // oc within group, 0..95
            int oc = g * OG_ + ol;
            float v = acc[mt][r];
            y[((size_t)b * OUT_ + oc) * N_ + n0 + col] = __float2bfloat16(v);
            float s = v, ss = v * v;
            #pragma unroll
            for (int m = 1; m <= 8; m <<= 1) {
                s  += __shfl_xor(s, m);
                ss += __shfl_xor(ss, m);
            }
            if (col == 0) {
                red[wid][ol]      = s;
                red[wid][96 + ol] = ss;
            }
        }
    }
    __syncthreads();
    if (tid < 192) {
        float t = red[0][tid] + red[1][tid] + red[2][tid] + red[3][tid];
        if (tid < 96) atomicAdd(&st[g * OG_ + tid], t);
        else          atomicAdd(&st[OUT_ + g * OG_ + (tid - 96)], t);
    }
}

// ---- Kernel E: BN (batch stats) + exact GELU, 8 elems/thread ----
__global__ __launch_bounds__(256) void k_bn_gelu(const __hip_bfloat16* __restrict__ y,
                                                 const float* __restrict__ st,
                                                 const float* __restrict__ gamma,
                                                 const float* __restrict__ beta,
                                                 float* __restrict__ out) {
    size_t base = ((size_t)blockIdx.x * 256 + threadIdx.x) * 8;
    int oc = (int)((base / N_) % OUT_);       // N_ % 8 == 0 -> uniform oc per 8
    const float invM = 1.0f / (float)(B_ * N_);
    float s = st[oc], ss = st[OUT_ + oc];
    float mean = s * invM;
    float var  = ss * invM - mean * mean;
    float inv  = 1.0f / sqrtf(var + 1e-5f);
    float sc = gamma[oc] * inv;
    float sh = beta[oc] - mean * sc;

    short8 v8 = *reinterpret_cast<const short8*>(y + base);
    float4 o0, o1;
    float* op0 = &o0.x;
    float* op1 = &o1.x;
    #pragma unroll
    for (int j = 0; j < 8; ++j) {
        unsigned int u = ((unsigned int)(unsigned short)v8[j]) << 16;
        float t = __builtin_bit_cast(float, u) * sc + sh;
        float r = 0.5f * t * (1.0f + erff(t * 0.70710678118654752f));
        if (j < 4) op0[j] = r; else op1[j - 4] = r;
    }
    *reinterpret_cast<float4*>(out + base)     = o0;
    *reinterpret_cast<float4*>(out + base + 4) = o1;
}

extern "C" void kernel_launch(void* const* d_in, const int* in_sizes, int n_in,
                              void* d_out, int out_size, void* d_ws, size_t ws_size,
                              hipStream_t stream) {
    const float* x      = (const float*)d_in[0];
    const int*   eidx   = (const int*)d_in[1];
    const float* conv_w = (const float*)d_in[2];
    // d_in[3] = conv_b: unused (bias cancels exactly under batch-stat BN)
    const float* gamma  = (const float*)d_in[4];
    const float* beta   = (const float*)d_in[5];
    float* out = (float*)d_out;

    char* ws = (char*)d_ws;
    __hip_bfloat16* xT = (__hip_bfloat16*)(ws + OFF_XT);
    __hip_bfloat16* wb = (__hip_bfloat16*)(ws + OFF_WB);
    float*          st = (float*)(ws + OFF_ST);
    __hip_bfloat16* y  = (__hip_bfloat16*)(ws + OFF_ST + 3072);

    k_transpose<<<dim3(B_, C_ / 64, N_ / 64), 256, 0, stream>>>(x, xT, conv_w, wb, st);
    k_conv<<<dim3(B_, G_, NTILES), 256, 0, stream>>>(xT, eidx, wb, y, st);
    k_bn_gelu<<<dim3((B_ * OUT_ * N_) / (256 * 8)), 256, 0, stream>>>(y, st, gamma, beta, out);
}